// Round 10
// baseline (126.229 us; speedup 1.0000x reference)
//
#include <hip/hip_runtime.h>

typedef unsigned short u16;
typedef __bf16 bf16x8 __attribute__((ext_vector_type(8)));
typedef __bf16 bf16x2 __attribute__((ext_vector_type(2)));
typedef unsigned short u16x8 __attribute__((ext_vector_type(8)));
typedef float f32x4 __attribute__((ext_vector_type(4)));
typedef int i32x4 __attribute__((ext_vector_type(4)));

#define MFMA16(a, b, c) __builtin_amdgcn_mfma_f32_16x16x32_bf16(a, b, c, 0, 0, 0)

#define GLDS16(gp, lp)                                                         \
  __builtin_amdgcn_global_load_lds(                                            \
      (const __attribute__((address_space(1))) unsigned int*)(gp),             \
      (__attribute__((address_space(3))) unsigned int*)(lp), 16, 0, 0)

__device__ __forceinline__ u16 f2bf(float f) {
  unsigned int u = __builtin_bit_cast(unsigned int, f);
  u += 0x7fffu + ((u >> 16) & 1u);
  return (u16)(u >> 16);
}

__device__ __forceinline__ f32x4 vmax4(f32x4 a, f32x4 b) {
  f32x4 r;
  r[0] = fmaxf(a[0], b[0]); r[1] = fmaxf(a[1], b[1]);
  r[2] = fmaxf(a[2], b[2]); r[3] = fmaxf(a[3], b[3]);
  return r;
}

// Q pre-scale: 1/sqrt(64) * log2(e)  (scores produced directly in log2 domain)
#define QSCALE 0.1803368842048386f

// ---------------- elementwise fp32 -> bf16 ----------------
__global__ void convert_x_kernel(const float* __restrict__ src,
                                 u16* __restrict__ dst, int n4) {
  int i = blockIdx.x * 256 + threadIdx.x;
  if (i < n4) {
    float4 v = ((const float4*)src)[i];
    ushort4 o;
    o.x = f2bf(v.x); o.y = f2bf(v.y); o.z = f2bf(v.z); o.w = f2bf(v.w);
    ((ushort4*)dst)[i] = o;
  }
}

// ---------------- transpose fp32 [K][N] -> bf16 [N][K] ----------------
__global__ void transpose_w_kernel(const float* __restrict__ src,
                                   u16* __restrict__ dst, int K, int N) {
  __shared__ float tile[32][33];
  const int n0 = blockIdx.x * 32, k0 = blockIdx.y * 32;
  const int t = threadIdx.x;
  const int r = t >> 3, c = (t & 7) * 4;
  float4 v = *(const float4*)&src[(size_t)(k0 + r) * N + n0 + c];
  tile[r][c + 0] = v.x; tile[r][c + 1] = v.y;
  tile[r][c + 2] = v.z; tile[r][c + 3] = v.w;
  __syncthreads();
  ushort4 o;
  o.x = f2bf(tile[c + 0][r]); o.y = f2bf(tile[c + 1][r]);
  o.z = f2bf(tile[c + 2][r]); o.w = f2bf(tile[c + 3][r]);
  *(ushort4*)&dst[(size_t)(n0 + r) * K + k0 + c] = o;
}

// ---------------- GEMM 128x128: A[M][K] bf16 rm, Bt[N][K] bf16 (B^T) --------
// qkv epilogue: Q,K head-split [b][h][s][d] (+bias, Q*=QSCALE);
// V stored TRANSPOSED [b][h][d][s] so attention can GLDS it directly.
__global__ __launch_bounds__(256) void gemm_qkv_kernel(
    const u16* __restrict__ A, const u16* __restrict__ Bt,
    const float* __restrict__ bias, u16* __restrict__ Qo,
    u16* __restrict__ Ko, u16* __restrict__ VoT, int K) {
  __shared__ __align__(16) u16 As[128 * 32];
  __shared__ __align__(16) u16 Bs[128 * 32];
  const int t = threadIdx.x;
  const int lane = t & 63;
  const int l15 = lane & 15, g = lane >> 4;
  const int w = t >> 6, wr = w >> 1, wc = w & 1;
  const int m0 = blockIdx.x * 128, n0 = blockIdx.y * 128;
  const int ar = t >> 2, ak = (t & 3) * 8;
  u16* AsW = As + (t & ~63) * 8;
  u16* BsW = Bs + (t & ~63) * 8;
  const u16* Ag = A + (size_t)(m0 + ar) * K + ak;
  const u16* Bg = Bt + (size_t)(n0 + ar) * K + ak;

  f32x4 acc[4][4] = {};
  for (int k0 = 0; k0 < K; k0 += 32) {
    __syncthreads();
    GLDS16(Ag + k0, AsW);
    GLDS16(Ag + (size_t)64 * K + k0, AsW + 2048);
    GLDS16(Bg + k0, BsW);
    GLDS16(Bg + (size_t)64 * K + k0, BsW + 2048);
    __syncthreads();
    bf16x8 af[4], bfr[4];
#pragma unroll
    for (int i = 0; i < 4; ++i)
      af[i] = *(const bf16x8*)&As[(wr * 64 + i * 16 + l15) * 32 + g * 8];
#pragma unroll
    for (int j = 0; j < 4; ++j)
      bfr[j] = *(const bf16x8*)&Bs[(wc * 64 + j * 16 + l15) * 32 + g * 8];
#pragma unroll
    for (int i = 0; i < 4; ++i)
#pragma unroll
      for (int j = 0; j < 4; ++j)
        acc[i][j] = MFMA16(af[i], bfr[j], acc[i][j]);
  }

#pragma unroll
  for (int j = 0; j < 4; ++j) {
    const int n = n0 + wc * 64 + j * 16 + l15;
    const float bv = bias[n];
    const int part = n >> 10, f = n & 1023;  // part uniform per wave
    const int hh = f >> 6, d = f & 63;
#pragma unroll
    for (int i = 0; i < 4; ++i) {
      const int mbase = m0 + wr * 64 + i * 16 + g * 4;
      const int bq = mbase >> 11, s = mbase & 2047;  // r=0..3 same b, s..s+3
      if (part == 2) {  // V^T: [b][h][d][s], s consecutive -> ushort4
        ushort4 o;
        o.x = f2bf(acc[i][j][0] + bv);
        o.y = f2bf(acc[i][j][1] + bv);
        o.z = f2bf(acc[i][j][2] + bv);
        o.w = f2bf(acc[i][j][3] + bv);
        *(ushort4*)&VoT[(((size_t)(bq * 16 + hh)) * 64 + d) * 2048 + s] = o;
      } else {
        u16* dst = (part == 0) ? Qo : Ko;
        const float sc = (part == 0) ? QSCALE : 1.f;
#pragma unroll
        for (int r = 0; r < 4; ++r)
          dst[(((size_t)(bq * 16 + hh)) * 2048 + (s + r)) * 64 + d] =
              f2bf((acc[i][j][r] + bv) * sc);
      }
    }
  }
}

// ---------------- GEMM 64x128 (proj): fp32 out[M][N], +bias -----------------
__global__ __launch_bounds__(256) void gemm_proj_kernel(
    const u16* __restrict__ A, const u16* __restrict__ Bt,
    const float* __restrict__ bias, float* __restrict__ outF, int N, int K) {
  __shared__ __align__(16) u16 As[64 * 32];
  __shared__ __align__(16) u16 Bs[128 * 32];
  const int t = threadIdx.x;
  const int lane = t & 63;
  const int l15 = lane & 15, g = lane >> 4;
  const int w = t >> 6, wr = w >> 1, wc = w & 1;
  const int m0 = blockIdx.x * 64, n0 = blockIdx.y * 128;
  const int ar = t >> 2, ak = (t & 3) * 8;
  u16* AsW = As + (t & ~63) * 8;
  u16* BsW = Bs + (t & ~63) * 8;
  const u16* Ag = A + (size_t)(m0 + ar) * K + ak;
  const u16* Bg = Bt + (size_t)(n0 + ar) * K + ak;

  f32x4 acc[2][4] = {};
  for (int k0 = 0; k0 < K; k0 += 32) {
    __syncthreads();
    // As is 64 rows x 32 k = 2048 u16 = 256 lanes x 8 u16: ALL threads stage.
    GLDS16(Ag + k0, AsW);
    GLDS16(Bg + k0, BsW);
    GLDS16(Bg + (size_t)64 * K + k0, BsW + 2048);
    __syncthreads();
    bf16x8 af[2], bfr[4];
#pragma unroll
    for (int i = 0; i < 2; ++i)
      af[i] = *(const bf16x8*)&As[(wr * 32 + i * 16 + l15) * 32 + g * 8];
#pragma unroll
    for (int j = 0; j < 4; ++j)
      bfr[j] = *(const bf16x8*)&Bs[(wc * 64 + j * 16 + l15) * 32 + g * 8];
#pragma unroll
    for (int i = 0; i < 2; ++i)
#pragma unroll
      for (int j = 0; j < 4; ++j)
        acc[i][j] = MFMA16(af[i], bfr[j], acc[i][j]);
  }

#pragma unroll
  for (int j = 0; j < 4; ++j) {
    const int n = n0 + wc * 64 + j * 16 + l15;
    const float bv = bias[j == j ? n : n];  // bias[n]
#pragma unroll
    for (int i = 0; i < 2; ++i) {
      const int mbase = m0 + wr * 32 + i * 16 + g * 4;
#pragma unroll
      for (int r = 0; r < 4; ++r)
        outF[(size_t)(mbase + r) * N + n] = acc[i][j][r] + bv;
    }
  }
}

// ---------------- flash attention (causal), bf16 MFMA, kv-split ------------
// grid (32 bh, 24 slots), block 512 (8 waves x 16 q-rows = 128-row q-tile),
// KVBLK=128. Slots: 0-7 = seg1 of tile slot+8 (kv [nt/2, nt), has diagonal);
// 8-15 = seg0 of tile slot-8+8 (kv [0, nt/2)); 16-23 = full tile 23-slot.
// CU c gets seg0+seg1 of ONE tile (sum nt=s+9) + full tile 7-s (nt=8-s):
// 17 iters/CU, max item 8 -> equal-length co-residency throughout.
// Segments write unnormalized O' (f32) + (m,l) partials; merge_kernel combines.
__global__ __launch_bounds__(512, 4) void attn_kernel(
    const u16* __restrict__ Qg, const u16* __restrict__ Kg,
    const u16* __restrict__ VTg, u16* __restrict__ Og,
    float* __restrict__ PO, float* __restrict__ ML) {
  __shared__ __align__(16) u16 Ks[2][128 * 64];  // K rows [kv][64 d]
  __shared__ __align__(16) u16 Vs[2][64 * 128];  // V^T rows [d][128 kv]

  const int bh = blockIdx.x;
  const int slot = blockIdx.y;
  int bx, seg;
  if (slot < 8)       { bx = slot + 8;  seg = 1; }
  else if (slot < 16) { bx = slot;      seg = 0; }   // tile slot (8..15)
  else                { bx = 23 - slot; seg = -1; }  // full tiles 7..0
  const int ntf = bx + 1, nh = ntf >> 1;
  const int kb = (seg == 1) ? nh : 0;
  const int ke = (seg == 0) ? nh : ntf;

  const int t = threadIdx.x;
  const int lane = t & 63, w = t >> 6;
  const int l15 = lane & 15, g = (lane >> 4) & 3;
  const bool ghi = (lane & 32) != 0;  // dest g>>1
  const int addrA = (l15 + 16 * ((2 * g) & 3)) << 2;      // bperm src, jj<2
  const int addrB = (l15 + 16 * ((2 * g + 1) & 3)) << 2;  // bperm src, jj>=2

  const size_t hb = (size_t)bh * (2048 * 64);
  const u16* Qh = Qg + hb;
  const u16* Kh = Kg + hb;
  const u16* VTh = VTg + hb;
  const int b = bh >> 4, h = bh & 15;

  // K staging (wave w: rows w*16 + {kr8, 8+kr8}; 8 chunks of 8 u16)
  const int kr8 = lane >> 3, cs = lane & 7;
  const int cl = cs ^ kr8;
  // V^T staging (wave w: d-rows {4w..4w+3, 32+4w..32+4w+3}; 16 chunks/row)
  const int vd = 4 * w + (lane >> 4);
  const int vcl = (lane & 15) ^ (vd & 7);  // (vd+32)&7 == vd&7

  const int q0 = bx * 128;
  const int qrow = q0 + w * 16 + l15;
  const bf16x8 qf0 = *(const bf16x8*)(Qh + (size_t)qrow * 64 + g * 8);
  const bf16x8 qf1 = *(const bf16x8*)(Qh + (size_t)qrow * 64 + 32 + g * 8);

  f32x4 oacc[4] = {};
  float mrow = -1e30f, lrow = 0.f;

#define STAGE(tile, bf)                                                        \
  do {                                                                         \
    const int kv0_ = (tile) * 128;                                             \
    GLDS16(Kh + (size_t)(kv0_ + w * 16 + kr8) * 64 + cl * 8,                   \
           &Ks[bf][w * 1024]);                                                 \
    GLDS16(Kh + (size_t)(kv0_ + w * 16 + 8 + kr8) * 64 + cl * 8,               \
           &Ks[bf][w * 1024 + 512]);                                           \
    GLDS16(VTh + (size_t)vd * 2048 + kv0_ + vcl * 8, &Vs[bf][w * 512]);        \
    GLDS16(VTh + (size_t)(vd + 32) * 2048 + kv0_ + vcl * 8,                    \
           &Vs[bf][w * 512 + 4096]);                                           \
  } while (0)

  STAGE(kb, 0);
  __syncthreads();

  for (int kt = kb; kt < ke; ++kt) {
    const int cur = (kt - kb) & 1;
    if (kt + 1 < ke) STAGE(kt + 1, cur ^ 1);

    // S^T = K Q^T : lane holds S[q=qrow][kv = cf*16 + g*4 + r], cf 0..7
    f32x4 sacc[8];
    const u16* Kc = &Ks[cur][0];
    const int sw = l15 & 7;
#pragma unroll
    for (int cf = 0; cf < 8; ++cf) {
      const int krow = cf * 16 + l15;
      const bf16x8 kf0 = *(const bf16x8*)&Kc[krow * 64 + (g ^ sw) * 8];
      const bf16x8 kf1 = *(const bf16x8*)&Kc[krow * 64 + ((g + 4) ^ sw) * 8];
      f32x4 z = {0.f, 0.f, 0.f, 0.f};
      z = MFMA16(kf0, qf0, z);
      z = MFMA16(kf1, qf1, z);
      sacc[cf] = z;
    }

    if (kt == bx) {  // diagonal 128x128 block: causal mask (seg1/full only)
      const int kv0 = kt * 128;
#pragma unroll
      for (int cf = 0; cf < 8; ++cf)
#pragma unroll
        for (int r = 0; r < 4; ++r) {
          const int kj = kv0 + cf * 16 + g * 4 + r;
          if (kj > qrow) sacc[cf][r] = -1e30f;
        }
    }

    // row max (tree) + cross-group reduce
    f32x4 m0v = vmax4(vmax4(sacc[0], sacc[1]), vmax4(sacc[2], sacc[3]));
    f32x4 m1v = vmax4(vmax4(sacc[4], sacc[5]), vmax4(sacc[6], sacc[7]));
    f32x4 mv = vmax4(m0v, m1v);
    float tm = fmaxf(fmaxf(mv[0], mv[1]), fmaxf(mv[2], mv[3]));
    tm = fmaxf(tm, __shfl_xor(tm, 16));
    tm = fmaxf(tm, __shfl_xor(tm, 32));

    if (!__all(tm <= mrow)) {  // defer-rescale (sc==1 exactly when skipped)
      const float mn = fmaxf(mrow, tm);
      const float sc = __builtin_amdgcn_exp2f(mrow - mn);
      mrow = mn;
      lrow *= sc;
#pragma unroll
      for (int f = 0; f < 4; ++f) oacc[f] *= sc;
    }

    float rs = 0.f;

#pragma unroll
    for (int hh = 0; hh < 2; ++hh) {
      // exp + pack: pk[cfl][s] covers kv = 64hh + 16cfl + 4g + 2s + {0,1}
      int pk[4][2];
#pragma unroll
      for (int cfl = 0; cfl < 4; ++cfl) {
        const int cf = hh * 4 + cfl;
#pragma unroll
        for (int r = 0; r < 4; ++r) {
          const float p = __builtin_amdgcn_exp2f(sacc[cf][r] - mrow);
          sacc[cf][r] = p;
          rs += p;
        }
#pragma unroll
        for (int s = 0; s < 2; ++s) {
          bf16x2 tp = {(__bf16)sacc[cf][2 * s], (__bf16)sacc[cf][2 * s + 1]};
          pk[cfl][s] = __builtin_bit_cast(int, tp);
        }
      }

#pragma unroll
      for (int clc = 0; clc < 2; ++clc) {
        // P^T B-frag: kv pair 64hh + 32clc + 8g + 2jj; fetch both cf
        // candidates from src lane g'=(2g+(jj>>1))&3, post-select by dest ghi
        int bfr[4];
#pragma unroll
        for (int jj = 0; jj < 4; ++jj) {
          const int addr = (jj >> 1) ? addrB : addrA;
          const int vlo =
              __builtin_amdgcn_ds_bpermute(addr, pk[2 * clc][jj & 1]);
          const int vhi =
              __builtin_amdgcn_ds_bpermute(addr, pk[2 * clc + 1][jj & 1]);
          bfr[jj] = ghi ? vhi : vlo;
        }
        const i32x4 bb = {bfr[0], bfr[1], bfr[2], bfr[3]};
        const bf16x8 pb = __builtin_bit_cast(bf16x8, bb);

        // O^T += V^T P^T ; va[k] = V^T[d = f*16+l15][kv = c*32 + g*8 + k]
        const int c = hh * 2 + clc;
#pragma unroll
        for (int f = 0; f < 4; ++f) {
          const int d = f * 16 + l15;
          const int ch = (c * 4 + g) ^ (d & 7);
          const bf16x8 va = *(const bf16x8*)&Vs[cur][d * 128 + ch * 8];
          oacc[f] = MFMA16(va, pb, oacc[f]);
        }
      }
    }

    rs += __shfl_xor(rs, 16);
    rs += __shfl_xor(rs, 32);
    lrow += rs;

    __syncthreads();  // reads of cur done; next tile's GLDS (vmcnt) drained
  }
#undef STAGE

  const int row = w * 16 + l15;
  if (seg < 0) {
    // full tile: write merged-head O[b][s][h*64 + d], d = f*16 + g*4 + r
    const float inv = 1.f / lrow;
#pragma unroll
    for (int f = 0; f < 4; ++f) {
      ushort4 o;
      o.x = __builtin_bit_cast(u16, (__bf16)(oacc[f][0] * inv));
      o.y = __builtin_bit_cast(u16, (__bf16)(oacc[f][1] * inv));
      o.z = __builtin_bit_cast(u16, (__bf16)(oacc[f][2] * inv));
      o.w = __builtin_bit_cast(u16, (__bf16)(oacc[f][3] * inv));
      *(ushort4*)&Og[((size_t)b * 2048 + qrow) * 1024 + h * 64 + f * 16 +
                     g * 4] = o;
    }
  } else {
    // segment: write unnormalized O' (f32) + per-row (m, l)
    const int item = (bh * 8 + (bx - 8)) * 2 + seg;
    float* po = PO + ((size_t)item * 128 + row) * 64;
#pragma unroll
    for (int f = 0; f < 4; ++f)
      *(f32x4*)&po[f * 16 + g * 4] = oacc[f];
    if ((lane >> 4) == 0) {  // one lane per q-row
      float2 ml2 = {mrow, lrow};
      *(float2*)&ML[((size_t)item * 128 + row) * 2] = ml2;
    }
  }
}

// ---------------- merge kv-split partials -> bf16 O ------------------------
// grid (32 bh * 8 tiles), 256 threads; thread = (row, d-half of 32)
__global__ __launch_bounds__(256) void merge_kernel(
    const float* __restrict__ PO, const float* __restrict__ ML,
    u16* __restrict__ Og) {
  const int blk = blockIdx.x;
  const int bh = blk >> 3, tm = blk & 7;
  const int bx = tm + 8;
  const int b = bh >> 4, h = bh & 15;
  const size_t item0 = (size_t)(bh * 8 + tm) * 2;
  const float* P0 = PO + item0 * (128 * 64);
  const float* P1 = P0 + 128 * 64;
  const float* M0 = ML + item0 * (128 * 2);
  const float* M1 = M0 + 128 * 2;
  const int t = threadIdx.x;
  const int row = t >> 1, dh = (t & 1) * 32;

  const float2 ml0 = *(const float2*)&M0[row * 2];
  const float2 ml1 = *(const float2*)&M1[row * 2];
  const float m = fmaxf(ml0.x, ml1.x);
  const float a0 = exp2f(ml0.x - m), a1 = exp2f(ml1.x - m);
  const float inv = 1.f / (a0 * ml0.y + a1 * ml1.y);
  const float c0 = a0 * inv, c1 = a1 * inv;

  const int q = bx * 128 + row;
  u16* dst = &Og[((size_t)b * 2048 + q) * 1024 + h * 64 + dh];
  const float* p0 = &P0[row * 64 + dh];
  const float* p1 = &P1[row * 64 + dh];
#pragma unroll
  for (int v = 0; v < 8; ++v) {
    const f32x4 x0 = *(const f32x4*)&p0[v * 4];
    const f32x4 x1 = *(const f32x4*)&p1[v * 4];
    ushort4 o;
    o.x = f2bf(c0 * x0[0] + c1 * x1[0]);
    o.y = f2bf(c0 * x0[1] + c1 * x1[1]);
    o.z = f2bf(c0 * x0[2] + c1 * x1[2]);
    o.w = f2bf(c0 * x0[3] + c1 * x1[3]);
    *(ushort4*)&dst[v * 4] = o;
  }
}

extern "C" void kernel_launch(void* const* d_in, const int* in_sizes, int n_in,
                              void* d_out, int out_size, void* d_ws,
                              size_t ws_size, hipStream_t stream) {
  const float* x = (const float*)d_in[0];       // [2,2048,1024]
  const float* w_attn = (const float*)d_in[1];  // [1024,3072]
  const float* b_attn = (const float*)d_in[2];  // [3072]
  const float* w_proj = (const float*)d_in[3];  // [1024,1024]
  const float* b_proj = (const float*)d_in[4];  // [1024]
  float* out = (float*)d_out;                   // [2,2048,1024] fp32

  char* ws = (char*)d_ws;
  u16* xb = (u16*)(ws);                          // 8 MB (reused as O later)
  u16* wT = (u16*)(ws + (8u << 20));             // 6 MB  [3072][1024]
  u16* wpT = (u16*)(ws + (14u << 20));           // 2 MB  [1024][1024]
  u16* Qb = (u16*)(ws + (16u << 20));            // 8 MB  [b][h][s][d]
  u16* Kb = (u16*)(ws + (24u << 20));            // 8 MB  [b][h][s][d]
  u16* VbT = (u16*)(ws + (32u << 20));           // 8 MB  [b][h][d][s]
  u16* Ob = xb;                                  // reuse xb region
  // kv-split partials: PO reuses d_out (16.78 MB, exact fit; proj overwrites
  // it afterwards in-stream); ML reuses the wT region (dead after qkv GEMM).
  float* PO = (float*)d_out;
  float* ML = (float*)(ws + (8u << 20));

  convert_x_kernel<<<4096, 256, 0, stream>>>(x, xb, 1048576);
  transpose_w_kernel<<<dim3(96, 32), 256, 0, stream>>>(w_attn, wT, 1024, 3072);
  transpose_w_kernel<<<dim3(32, 32), 256, 0, stream>>>(w_proj, wpT, 1024, 1024);

  gemm_qkv_kernel<<<dim3(32, 24), 256, 0, stream>>>(xb, wT, b_attn, Qb, Kb,
                                                    VbT, 1024);

  attn_kernel<<<dim3(32, 24), 512, 0, stream>>>(Qb, Kb, VbT, Ob, PO, ML);

  merge_kernel<<<256, 256, 0, stream>>>(PO, ML, Ob);

  gemm_proj_kernel<<<dim3(64, 8), 256, 0, stream>>>(Ob, wpT, b_proj, out,
                                                    1024, 1024);
}